// Round 1
// baseline (61.991 us; speedup 1.0000x reference)
//
#include <hip/hip_runtime.h>
#include <math.h>

#define NN 2048
#define INDIM 256
#define ODIM 64
#define NH 8
#define DHD 8

// Kernel 1: wh = h @ W^T + b ; ei[n,h] = dot(wh[n,h*8..],aL)+ab ; ej[n,h] = dot(.,aR)
// One wave per node (lane = output column o), 4 nodes per 256-thread block.
__global__ __launch_bounds__(256) void gat_pre(
    const float* __restrict__ h, const float* __restrict__ Ww,
    const float* __restrict__ Wb, const float* __restrict__ aw,
    const float* __restrict__ ab,
    float* __restrict__ wh, float* __restrict__ ei, float* __restrict__ ej)
{
    const int t = threadIdx.x;
    const int wv = t >> 6;          // wave in block -> node
    const int o  = t & 63;          // output column
    const int n  = blockIdx.x * 4 + wv;

    const float4* h4 = (const float4*)(h + (size_t)n * INDIM);
    const float4* w4 = (const float4*)(Ww + (size_t)o * INDIM);
    float acc = 0.f;
#pragma unroll 8
    for (int k = 0; k < INDIM / 4; ++k) {
        const float4 hv = h4[k];
        const float4 wvv = w4[k];
        acc = fmaf(hv.x, wvv.x, acc);
        acc = fmaf(hv.y, wvv.y, acc);
        acc = fmaf(hv.z, wvv.z, acc);
        acc = fmaf(hv.w, wvv.w, acc);
    }
    acc += Wb[o];
    wh[(size_t)n * ODIM + o] = acc;

    const int d = o & 7;
    float pi = acc * aw[d];         // aL
    float pj = acc * aw[8 + d];     // aR
#pragma unroll
    for (int m = 1; m < 8; m <<= 1) {
        pi += __shfl_xor(pi, m, 64);
        pj += __shfl_xor(pj, m, 64);
    }
    if (d == 0) {
        const int hh = o >> 3;
        ei[n * NH + hh] = pi + ab[0];   // fold bias into ei
        ej[n * NH + hh] = pj;
    }
}

// Kernel 2: per node i, softmax over neighbors j and PV accumulate.
// 256 threads = 32 j-lanes x 8 heads. No max-subtraction needed (scores bounded,
// non-edges contribute exactly 0 as in the reference's exp(NEG_BIG-max)=0).
__global__ __launch_bounds__(256) void gat_main(
    const int* __restrict__ adj, const float* __restrict__ wh,
    const float* __restrict__ ei, const float* __restrict__ ej,
    float* __restrict__ out)
{
    __shared__ int s_adj[NN];                // 8 KB
    __shared__ float s_red[4][8][9];         // per-wave partials
    const int i = blockIdx.x;
    const int t = threadIdx.x;

    {   // stage adjacency row (coalesced int4)
        const int4* arow = (const int4*)(adj + (size_t)i * NN);
        int4* sa = (int4*)s_adj;
        sa[t]       = arow[t];
        sa[t + 256] = arow[t + 256];
    }
    __syncthreads();

    const int hh = t & 7;
    const int jj = t >> 3;                   // 0..31
    const float eih = ei[i * NH + hh];

    float den = 0.f;
    float a0=0.f,a1=0.f,a2=0.f,a3=0.f,a4=0.f,a5=0.f,a6=0.f,a7=0.f;

#pragma unroll 4
    for (int st = 0; st < NN / 32; ++st) {
        const int j = (st << 5) | jj;
        if (s_adj[j] != 0) {
            float sc = eih + ej[j * NH + hh];
            sc = fmaxf(sc, 0.2f * sc);       // LeakyReLU(0.2)
            const float w = __expf(sc);
            den += w;
            const float4* wr = (const float4*)(wh + (size_t)j * ODIM + hh * DHD);
            const float4 w0 = wr[0];
            const float4 w1 = wr[1];
            a0 = fmaf(w, w0.x, a0); a1 = fmaf(w, w0.y, a1);
            a2 = fmaf(w, w0.z, a2); a3 = fmaf(w, w0.w, a3);
            a4 = fmaf(w, w1.x, a4); a5 = fmaf(w, w1.y, a5);
            a6 = fmaf(w, w1.z, a6); a7 = fmaf(w, w1.w, a7);
        }
    }

    // reduce over jj: lane bits 3..5 within wave (xor 8,16,32)
#pragma unroll
    for (int m = 8; m <= 32; m <<= 1) {
        den += __shfl_xor(den, m, 64);
        a0 += __shfl_xor(a0, m, 64);  a1 += __shfl_xor(a1, m, 64);
        a2 += __shfl_xor(a2, m, 64);  a3 += __shfl_xor(a3, m, 64);
        a4 += __shfl_xor(a4, m, 64);  a5 += __shfl_xor(a5, m, 64);
        a6 += __shfl_xor(a6, m, 64);  a7 += __shfl_xor(a7, m, 64);
    }
    const int lane = t & 63;
    const int wv = t >> 6;
    if (lane < 8) {                          // lane == head
        s_red[wv][lane][0] = a0; s_red[wv][lane][1] = a1;
        s_red[wv][lane][2] = a2; s_red[wv][lane][3] = a3;
        s_red[wv][lane][4] = a4; s_red[wv][lane][5] = a5;
        s_red[wv][lane][6] = a6; s_red[wv][lane][7] = a7;
        s_red[wv][lane][8] = den;
    }
    __syncthreads();

    if (t < 64) {
        const int oh = t >> 3;
        const int d  = t & 7;
        const float v  = s_red[0][oh][d] + s_red[1][oh][d]
                       + s_red[2][oh][d] + s_red[3][oh][d];
        const float dn = s_red[0][oh][8] + s_red[1][oh][8]
                       + s_red[2][oh][8] + s_red[3][oh][8];
        float r = v / dn;
        r = (r > 0.f) ? r : expm1f(r);       // ELU(alpha=1)
        // output flat layout: (H, N, Dh) -> reshape(-1, 64)
        out[(size_t)oh * (NN * DHD) + (size_t)i * DHD + d] = r;
    }
}

extern "C" void kernel_launch(void* const* d_in, const int* in_sizes, int n_in,
                              void* d_out, int out_size, void* d_ws, size_t ws_size,
                              hipStream_t stream) {
    const float* h   = (const float*)d_in[0];
    const int*   adj = (const int*)d_in[1];
    const float* Ww  = (const float*)d_in[2];
    const float* Wb  = (const float*)d_in[3];
    const float* aw  = (const float*)d_in[4];
    const float* ab  = (const float*)d_in[5];
    float* out = (float*)d_out;

    float* wh = (float*)d_ws;                 // 2048*64 f32
    float* ei = wh + (size_t)NN * ODIM;       // 2048*8
    float* ej = ei + (size_t)NN * NH;         // 2048*8

    gat_pre<<<NN / 4, 256, 0, stream>>>(h, Ww, Wb, aw, ab, wh, ei, ej);
    gat_main<<<NN, 256, 0, stream>>>(adj, wh, ei, ej, out);
}

// Round 2
// 40.600 us; speedup vs baseline: 1.5269x; 1.5269x over previous
//
#include <hip/hip_runtime.h>
#include <math.h>

#define NN 2048
#define INDIM 256
#define ODIM 64
#define NH 8
#define DHD 8
#define LOG2E 1.44269504088896340736f

// K1: wh = h@W^T + b ; eiL = (ei + ab)*log2e ; ejL = ej*log2e
// grid 128 x 256 threads; 16 nodes per block, 4 nodes per wave (lane = out col).
__global__ __launch_bounds__(256) void gat_pre(
    const float* __restrict__ h, const float* __restrict__ Ww,
    const float* __restrict__ Wb, const float* __restrict__ aw,
    const float* __restrict__ ab,
    float* __restrict__ wh, float* __restrict__ eiL, float* __restrict__ ejL)
{
    __shared__ float sH[16][INDIM];          // 16 KB
    const int t = threadIdx.x;
    const int n0 = blockIdx.x * 16;
    {
        const float4* src = (const float4*)(h + (size_t)n0 * INDIM);
        float4* dst = (float4*)&sH[0][0];
#pragma unroll
        for (int k = 0; k < 4; ++k) dst[t + k * 256] = src[t + k * 256];
    }
    __syncthreads();

    const int o  = t & 63;
    const int wv = t >> 6;
    const int nb = wv * 4;                   // 4 nodes per wave
    const float4* w4 = (const float4*)(Ww + (size_t)o * INDIM);
    float a0 = 0.f, a1 = 0.f, a2 = 0.f, a3 = 0.f;
#pragma unroll 4
    for (int k = 0; k < INDIM / 4; ++k) {
        const float4 wk = w4[k];
        const float4 h0 = *(const float4*)&sH[nb + 0][k * 4];
        const float4 h1 = *(const float4*)&sH[nb + 1][k * 4];
        const float4 h2 = *(const float4*)&sH[nb + 2][k * 4];
        const float4 h3 = *(const float4*)&sH[nb + 3][k * 4];
        a0 = fmaf(wk.x, h0.x, a0); a0 = fmaf(wk.y, h0.y, a0);
        a0 = fmaf(wk.z, h0.z, a0); a0 = fmaf(wk.w, h0.w, a0);
        a1 = fmaf(wk.x, h1.x, a1); a1 = fmaf(wk.y, h1.y, a1);
        a1 = fmaf(wk.z, h1.z, a1); a1 = fmaf(wk.w, h1.w, a1);
        a2 = fmaf(wk.x, h2.x, a2); a2 = fmaf(wk.y, h2.y, a2);
        a2 = fmaf(wk.z, h2.z, a2); a2 = fmaf(wk.w, h2.w, a2);
        a3 = fmaf(wk.x, h3.x, a3); a3 = fmaf(wk.y, h3.y, a3);
        a3 = fmaf(wk.z, h3.z, a3); a3 = fmaf(wk.w, h3.w, a3);
    }
    const float bias = Wb[o];
    float accs[4] = {a0 + bias, a1 + bias, a2 + bias, a3 + bias};

    const int d = o & 7;
    const float aL = aw[d], aR = aw[NH + d];
    const float abv = ab[0];
#pragma unroll
    for (int r = 0; r < 4; ++r) {
        const int n = n0 + nb + r;
        wh[(size_t)n * ODIM + o] = accs[r];
        float pi = accs[r] * aL;
        float pj = accs[r] * aR;
        pi += __shfl_xor(pi, 1, 64); pj += __shfl_xor(pj, 1, 64);
        pi += __shfl_xor(pi, 2, 64); pj += __shfl_xor(pj, 2, 64);
        pi += __shfl_xor(pi, 4, 64); pj += __shfl_xor(pj, 4, 64);
        if (d == 0) {
            const int hd = o >> 3;
            eiL[n * NH + hd] = (pi + abv) * LOG2E;
            ejL[n * NH + hd] = pj * LOG2E;
        }
    }
}

// K2: 8 i-rows per block. 512 threads = 64 j-lanes x 8 heads.
// adj rows staged in LDS as float 0/1 masks -> branchless edge loop.
__global__ __launch_bounds__(512, 2) void gat_main(
    const int* __restrict__ adj, const float* __restrict__ wh,
    const float* __restrict__ eiL, const float* __restrict__ ejL,
    float* __restrict__ out)
{
    __shared__ float s_adj[8 * NN];          // 64 KB float masks
    __shared__ float s_red[8][8][8][9];      // 18 KB: wave, head, i, d/den
    const int t  = threadIdx.x;
    const int i0 = blockIdx.x * 8;

    {   // stage + int->float convert, coalesced int4
        const int4* arow = (const int4*)(adj + (size_t)i0 * NN);
        float4* sa = (float4*)s_adj;
#pragma unroll
        for (int k = 0; k < 8; ++k) {
            const int4 v = arow[t + k * 512];
            sa[t + k * 512] = make_float4((float)v.x, (float)v.y, (float)v.z, (float)v.w);
        }
    }
    __syncthreads();

    const int hh = t & 7;
    const int jj = t >> 3;                   // 0..63
    float eih[8];
#pragma unroll
    for (int i = 0; i < 8; ++i) eih[i] = eiL[(i0 + i) * NH + hh];

    float den[8];
    float acc[8][8];
#pragma unroll
    for (int i = 0; i < 8; ++i) {
        den[i] = 0.f;
#pragma unroll
        for (int d2 = 0; d2 < 8; ++d2) acc[i][d2] = 0.f;
    }

#pragma unroll 2
    for (int it = 0; it < NN / 64; ++it) {
        const int j = (it << 6) | jj;
        const float ejv = ejL[j * NH + hh];
        const float4* wr = (const float4*)(wh + (size_t)j * ODIM + hh * DHD);
        const float4 w0 = wr[0];
        const float4 w1 = wr[1];
#pragma unroll
        for (int i = 0; i < 8; ++i) {
            float s = eih[i] + ejv;          // score * log2e
            s = fmaxf(s, 0.2f * s);          // LeakyReLU (commutes with +scale)
            float w = exp2f(s) * s_adj[i * NN + j];
            den[i] += w;
            acc[i][0] = fmaf(w, w0.x, acc[i][0]);
            acc[i][1] = fmaf(w, w0.y, acc[i][1]);
            acc[i][2] = fmaf(w, w0.z, acc[i][2]);
            acc[i][3] = fmaf(w, w0.w, acc[i][3]);
            acc[i][4] = fmaf(w, w1.x, acc[i][4]);
            acc[i][5] = fmaf(w, w1.y, acc[i][5]);
            acc[i][6] = fmaf(w, w1.z, acc[i][6]);
            acc[i][7] = fmaf(w, w1.w, acc[i][7]);
        }
    }

    // reduce over the 8 j-lane groups within each wave (lane bits 3..5)
#pragma unroll
    for (int m = 8; m <= 32; m <<= 1) {
#pragma unroll
        for (int i = 0; i < 8; ++i) {
            den[i] += __shfl_xor(den[i], m, 64);
#pragma unroll
            for (int d2 = 0; d2 < 8; ++d2)
                acc[i][d2] += __shfl_xor(acc[i][d2], m, 64);
        }
    }
    const int lane = t & 63;
    const int wv   = t >> 6;
    if (lane < 8) {                          // lane == head
#pragma unroll
        for (int i = 0; i < 8; ++i) {
#pragma unroll
            for (int d2 = 0; d2 < 8; ++d2) s_red[wv][lane][i][d2] = acc[i][d2];
            s_red[wv][lane][i][8] = den[i];
        }
    }
    __syncthreads();

    {   // 512 threads = 8 i x 8 heads x 8 d
        const int i  = t >> 6;
        const int oh = (t >> 3) & 7;
        const int d2 = t & 7;
        float v = 0.f, dn = 0.f;
#pragma unroll
        for (int w2 = 0; w2 < 8; ++w2) {
            v  += s_red[w2][oh][i][d2];
            dn += s_red[w2][oh][i][8];
        }
        float r = v / dn;
        r = (r > 0.f) ? r : expm1f(r);       // ELU(alpha=1)
        out[(size_t)oh * (NN * DHD) + (size_t)(i0 + i) * DHD + d2] = r;
    }
}

extern "C" void kernel_launch(void* const* d_in, const int* in_sizes, int n_in,
                              void* d_out, int out_size, void* d_ws, size_t ws_size,
                              hipStream_t stream) {
    const float* h   = (const float*)d_in[0];
    const int*   adj = (const int*)d_in[1];
    const float* Ww  = (const float*)d_in[2];
    const float* Wb  = (const float*)d_in[3];
    const float* aw  = (const float*)d_in[4];
    const float* ab  = (const float*)d_in[5];
    float* out = (float*)d_out;

    float* wh  = (float*)d_ws;                // 2048*64 f32
    float* eiL = wh + (size_t)NN * ODIM;      // 2048*8
    float* ejL = eiL + (size_t)NN * NH;       // 2048*8

    gat_pre<<<NN / 16, 256, 0, stream>>>(h, Ww, Wb, aw, ab, wh, eiL, ejL);
    gat_main<<<NN / 8, 512, 0, stream>>>(adj, wh, eiL, ejL, out);
}